// Round 8
// baseline (871.535 us; speedup 1.0000x reference)
//
#include <hip/hip_runtime.h>
#include <hip/hip_cooperative_groups.h>
#include <cstdint>
#include <cstddef>

namespace cg = cooperative_groups;

#define N_NODES 50000
#define N_EDGES 300000
#define DIM     256
#define KTOT    768   // concatenated K: [agg*norm | h | prev_h]
#define N_RELS  500

#define SCAN_NBLK ((N_NODES + 255) / 256)   // 196
#define WT_BLKS   48                        // 3 mats x (4x4) 64x64 tiles
#define COOP_BLKS 1024                      // 4 blocks/CU — safely co-resident

#define CONV_ELEMS ((N_NODES + N_RELS) * DIM)

typedef unsigned short u16;
typedef __attribute__((ext_vector_type(8))) short short8v;   // 8 bf16 = 4 VGPRs (MFMA A/B frag)
typedef __attribute__((ext_vector_type(4))) float float4v;   // MFMA C/D frag

static __device__ __forceinline__ u16 f2bf(float f) {
    union { float f; unsigned u; } v; v.f = f;
    unsigned u = v.u;
    unsigned r = u + 0x7FFFu + ((u >> 16) & 1u);  // RNE
    return (u16)(r >> 16);
}
static __device__ __forceinline__ float bf2f(u16 b) {
    union { unsigned u; float f; } v; v.u = ((unsigned)b) << 16; return v.f;
}

// async global->LDS, 16B per lane, LDS dest = wave-uniform base + lane*16 (linear)
static __device__ __forceinline__ void gld16(const void* g, u16* l) {
    __builtin_amdgcn_global_load_lds(
        (const __attribute__((address_space(1))) unsigned int*)g,
        (__attribute__((address_space(3))) unsigned int*)l,
        16, 0, 0);
}

// unpack 2x uint4 (8+8 bf16) and accumulate into 8 floats
static __device__ __forceinline__ void acc8(float* a, uint4 hv, uint4 ev) {
    const unsigned* hw = (const unsigned*)&hv;
    const unsigned* ew = (const unsigned*)&ev;
#pragma unroll
    for (int j = 0; j < 4; j++) {
        a[2*j]   += bf2f((u16)(hw[j] & 0xffffu)) + bf2f((u16)(ew[j] & 0xffffu));
        a[2*j+1] += bf2f((u16)(hw[j] >> 16))     + bf2f((u16)(ew[j] >> 16));
    }
}

// ---------------- K1 (cooperative): zero + conv + Wt + hist + scan + scatter ----------------
// Replaces 2 memsets + prep + scanA/B/C + scatter (7 graph nodes -> 1). Each phase keeps
// its proven parallel structure; grid.sync() provides the cross-phase ordering that
// previously cost a full launch gap each. 1024 blocks x 256 thr = 4 blocks/CU (LDS
// 17.6KB -> 70KB/CU at 4 blocks; __launch_bounds__(256,4) caps VGPR at 128: safe).
__global__ void __launch_bounds__(256, 4)
csr_kernel(const float* __restrict__ h, const float* __restrict__ emb,
           const float* __restrict__ Wn, const float* __restrict__ Wl,
           const float* __restrict__ Wsc,
           const int* __restrict__ src, const int* __restrict__ dstv,
           const int* __restrict__ et,
           u16* __restrict__ Xh, u16* __restrict__ embb, u16* __restrict__ Wt,
           int* __restrict__ deg, int* __restrict__ wlcnt,
           int* __restrict__ excl, int* __restrict__ bsum, int* __restrict__ bbase,
           int* __restrict__ offsets, int* __restrict__ cursor,
           unsigned* __restrict__ esee) {
    cg::grid_group grid = cg::this_grid();
    __shared__ float T[64][65];   // Wt transpose tile (phase 0)
    __shared__ int   sdata[256];  // scan scratch (phases 2/3)
    int t = threadIdx.x;
    int gtid = blockIdx.x * 256 + t;
    const int gsz = COOP_BLKS * 256;

    // ---- Phase 0a: zero deg + wlcnt (replaces the 2 hipMemsetAsync) ----
    for (int i = gtid; i < N_NODES; i += gsz) deg[i] = 0;
    if (gtid == 0) wlcnt[0] = 0;

    // ---- Phase 0b: conv h -> Xh bf16, emb -> embb bf16 (grid-stride) ----
    for (int i = gtid; i < CONV_ELEMS / 8; i += gsz) {
        int e0 = i * 8;
        const float* s; u16* d;
        if (e0 < N_NODES * DIM) { s = h + e0; d = Xh + e0; }
        else { int o = e0 - N_NODES * DIM; s = emb + o; d = embb + o; }
        float4 a = *(const float4*)(s);
        float4 c2 = *(const float4*)(s + 4);
        u16 o8[8] = { f2bf(a.x), f2bf(a.y), f2bf(a.z), f2bf(a.w),
                      f2bf(c2.x), f2bf(c2.y), f2bf(c2.z), f2bf(c2.w) };
        *(uint4*)d = *(const uint4*)o8;
    }

    // ---- Phase 0c: Wt[d][k] = Wseg[k%256][d] via LDS 64x64 transpose (blocks 0..47) ----
    if (blockIdx.x < WT_BLKS) {
        int tb  = blockIdx.x;
        int mat = tb >> 4;                 // 0..2
        int kb  = (tb & 15) >> 2;          // k-tile 0..3
        int db  = tb & 3;                  // d-tile 0..3
        const float* W = (mat == 0) ? Wn : ((mat == 1) ? Wl : Wsc);
        int c  = t & 63;
        int rq = t >> 6;                   // 0..3
#pragma unroll
        for (int p = 0; p < 16; p++) {
            int kk = rq + p * 4;
            T[kk][c] = W[(kb * 64 + kk) * DIM + db * 64 + c];
        }
        __syncthreads();
#pragma unroll
        for (int p = 0; p < 16; p++) {
            int dd = rq + p * 4;
            Wt[(size_t)(db * 64 + dd) * KTOT + mat * 256 + kb * 64 + c] = f2bf(T[c][dd]);
        }
    }
    grid.sync();

    // ---- Phase 1: in-degree histogram ----
    for (int e = gtid; e < N_EDGES; e += gsz) atomicAdd(&deg[dstv[e]], 1);
    grid.sync();

    // ---- Phase 2: per-chunk scan (blocks 0..195, the proven scanA structure) ----
    if (blockIdx.x < SCAN_NBLK) {
        int i = blockIdx.x * 256 + t;
        int v = (i < N_NODES) ? deg[i] : 0;
        sdata[t] = v;
        __syncthreads();
        for (int off = 1; off < 256; off <<= 1) {
            int u = (t >= off) ? sdata[t - off] : 0;
            __syncthreads();
            sdata[t] += u;
            __syncthreads();
        }
        if (i < N_NODES) excl[i] = sdata[t] - v;
        if (t == 255) bsum[blockIdx.x] = sdata[t];
    }
    grid.sync();

    // ---- Phase 3: scan the 196 chunk sums (block 0) ----
    if (blockIdx.x == 0) {
        int v = (t < SCAN_NBLK) ? bsum[t] : 0;
        sdata[t] = v;
        __syncthreads();
        for (int off = 1; off < 256; off <<= 1) {
            int u = (t >= off) ? sdata[t - off] : 0;
            __syncthreads();
            sdata[t] += u;
            __syncthreads();
        }
        if (t < SCAN_NBLK) bbase[t] = sdata[t] - v;
        if (t == SCAN_NBLK - 1) offsets[N_NODES] = sdata[t];
    }
    grid.sync();

    // ---- Phase 4: combine -> offsets, cursor (grid-stride) ----
    for (int i = gtid; i < N_NODES; i += gsz) {
        int e = bbase[i >> 8] + excl[i];
        offsets[i] = e; cursor[i] = e;
    }
    grid.sync();

    // ---- Phase 5: scatter edges into CSR slots ----
    for (int e = gtid; e < N_EDGES; e += gsz) {
        int d = dstv[e];
        int pos = atomicAdd(&cursor[d], 1);
        esee[pos] = (unsigned)src[e] * N_RELS + (unsigned)et[e];
    }
}

// ---------------- K2: gather-reduce, 2 nodes/wave, 16B loads -> Xa; prev_h -> Xp ----------
// 32 lanes per node, uint4 (8 bf16) per lane; 8 outstanding 16B loads/lane in the 4-edge
// unroll. prev_h conversion streams under the gather latency. (unchanged from R7)
__global__ void agg_kernel(const u16* __restrict__ Xh, const u16* __restrict__ embb,
                           const float* __restrict__ norm, const int* __restrict__ offsets,
                           const unsigned* __restrict__ esee, const float* __restrict__ prev_h,
                           u16* __restrict__ Xa, u16* __restrict__ Xp,
                           int* __restrict__ wl_count, int* __restrict__ wl) {
    int wave = (blockIdx.x * 256 + threadIdx.x) >> 6;
    int half = (threadIdx.x >> 5) & 1;
    int lane32 = threadIdx.x & 31;
    int n = wave * 2 + half;
    if (n >= N_NODES) return;
    int s0 = offsets[n], s1 = offsets[n + 1];
    int c8 = lane32 * 8;
    // prev_h conversion loads issued early — overlap the gather chain
    float4 pa = *(const float4*)(prev_h + (size_t)n * DIM + c8);
    float4 pb = *(const float4*)(prev_h + (size_t)n * DIM + c8 + 4);
    float acc[8] = {0.f, 0.f, 0.f, 0.f, 0.f, 0.f, 0.f, 0.f};
    int e = s0;
    for (; e + 3 < s1; e += 4) {
        unsigned v0 = esee[e], v1 = esee[e + 1], v2 = esee[e + 2], v3 = esee[e + 3];
        unsigned sa = v0 / N_RELS, ta = v0 - sa * N_RELS;
        unsigned sb = v1 / N_RELS, tb = v1 - sb * N_RELS;
        unsigned sc = v2 / N_RELS, tc = v2 - sc * N_RELS;
        unsigned sd = v3 / N_RELS, td = v3 - sd * N_RELS;
        uint4 ha = *(const uint4*)(Xh + (size_t)sa * DIM + c8);
        uint4 ea = *(const uint4*)(embb + (size_t)ta * DIM + c8);
        uint4 hb = *(const uint4*)(Xh + (size_t)sb * DIM + c8);
        uint4 eb = *(const uint4*)(embb + (size_t)tb * DIM + c8);
        uint4 hc = *(const uint4*)(Xh + (size_t)sc * DIM + c8);
        uint4 ec = *(const uint4*)(embb + (size_t)tc * DIM + c8);
        uint4 hd = *(const uint4*)(Xh + (size_t)sd * DIM + c8);
        uint4 ed = *(const uint4*)(embb + (size_t)td * DIM + c8);
        acc8(acc, ha, ea); acc8(acc, hb, eb); acc8(acc, hc, ec); acc8(acc, hd, ed);
    }
    for (; e < s1; e++) {
        unsigned v = esee[e];
        unsigned s = v / N_RELS;
        unsigned t = v - s * N_RELS;
        uint4 hv = *(const uint4*)(Xh + (size_t)s * DIM + c8);
        uint4 ev = *(const uint4*)(embb + (size_t)t * DIM + c8);
        acc8(acc, hv, ev);
    }
    float nr = norm[n];
    u16 o[8];
#pragma unroll
    for (int j = 0; j < 8; j++) o[j] = f2bf(acc[j] * nr);
    *(uint4*)(Xa + (size_t)n * DIM + c8) = *(const uint4*)o;
    u16 p8[8] = { f2bf(pa.x), f2bf(pa.y), f2bf(pa.z), f2bf(pa.w),
                  f2bf(pb.x), f2bf(pb.y), f2bf(pb.z), f2bf(pb.w) };
    *(uint4*)(Xp + (size_t)n * DIM + c8) = *(const uint4*)p8;
    if (lane32 == 0 && s1 == s0) { int idx = atomicAdd(wl_count, 1); wl[idx] = n; }
}

// ---------------- K3: fused MFMA GEMM, counted-vmcnt, 8-wave high-occupancy ----------------
// R4 proven structure, unchanged. A sources: Xa kt0-3, Xh kt4-7, Xp kt8-11 (compile-time
// select under the unrolled kt loop). 5 gld16/thread/tile; head waits vmcnt(5) (T4).
// Swizzle: source chunk pre-XOR (lc8^lr), linear LDS dest, read chunk XOR (m16&7)<<3.
// LDS: A dbuf 2x8KB @u16[0/4096], B dbuf 2x32KB @u16[8192/24576] = 80KB -> 2 blocks/CU.
__launch_bounds__(512, 4)
__global__ void gemm_kernel(const u16* __restrict__ Xa, const u16* __restrict__ Xh,
                            const u16* __restrict__ Xp, const u16* __restrict__ Wt,
                            const float* __restrict__ prev_h, const float* __restrict__ bias,
                            float* __restrict__ out) {
    __shared__ __align__(16) u16 lds[40960];   // 81920 B
    int tid  = threadIdx.x;
    int wave = tid >> 6, lane = tid & 63, q = lane >> 4, m16 = lane & 15;
    int wm = wave >> 2;              // M-group: rows [wm*32, +32)
    int wnn = (wave & 3) * 64;       // N-group: cols [wnn, +64)
    int m0 = blockIdx.x * 64;
    int lr = lane >> 3, lc8 = lane & 7;        // staging: row-in-issue / 16B-chunk
    int sc8 = (lc8 ^ lr) << 3;                 // pre-swizzled source chunk (u16 units)

    // A staging: wave stages rows [wave*8, +8)  (8 waves cover 64 rows)
    int arow = wave * 8 + lr;
    int ga = (m0 + arow < N_NODES) ? (m0 + arow) : (N_NODES - 1);
    const u16* sAa = Xa + (size_t)ga * DIM + sc8;
    const u16* sAh = Xh + (size_t)ga * DIM + sc8;
    const u16* sAp = Xp + (size_t)ga * DIM + sc8;
    // B staging: wave stages Wt rows [wave*32, +32) in 4 issues of 8 rows
    const u16* sB = Wt + (size_t)(wave * 32 + lr) * KTOT + sc8;

    float4v acc1[2][4], acc2[2][4];
#pragma unroll
    for (int i = 0; i < 2; i++)
#pragma unroll
        for (int j = 0; j < 4; j++) { acc1[i][j] = (float4v)0.f; acc2[i][j] = (float4v)0.f; }

    auto stage = [&](int kt, int buf) {
#pragma unroll
        for (int j = 0; j < 4; j++)
            gld16(sB + (size_t)j * 8 * KTOT + kt * 64,
                  &lds[8192 + buf * 16384 + wave * 2048 + j * 512]);
        const u16* base = (kt < 4) ? sAa : ((kt < 8) ? sAh : sAp);
        gld16(base + (kt & 3) * 64, &lds[buf * 4096 + wave * 512]);
    };

    // prologue: tiles 0 and 1 in flight (10 outstanding per thread)
    stage(0, 0);
    stage(1, 1);

    int sw = (m16 & 7) << 3;   // read-side swizzle (u16 units)

#pragma unroll
    for (int kt = 0; kt < 12; kt++) {
        int buf = kt & 1;
        // wait for MY tile-kt loads only; tile-kt+1's 5 stay in flight (T4)
        if (kt < 11) asm volatile("s_waitcnt vmcnt(5)" ::: "memory");
        else         asm volatile("s_waitcnt vmcnt(0)" ::: "memory");
        __builtin_amdgcn_sched_barrier(0);
        __builtin_amdgcn_s_barrier();          // every wave's tile-kt data now in LDS
        __builtin_amdgcn_sched_barrier(0);

#pragma unroll
        for (int kk = 0; kk < 2; kk++) {
            int ck = (kk * 32 + q * 8) ^ sw;
            short8v af[2], bfr[4];
#pragma unroll
            for (int mi = 0; mi < 2; mi++)
                af[mi] = *(const short8v*)(&lds[buf * 4096 + (wm * 32 + mi * 16 + m16) * 64 + ck]);
#pragma unroll
            for (int ni = 0; ni < 4; ni++)
                bfr[ni] = *(const short8v*)(&lds[8192 + buf * 16384 + (wnn + ni * 16 + m16) * 64 + ck]);
            if (kt < 8) {
#pragma unroll
                for (int mi = 0; mi < 2; mi++)
#pragma unroll
                    for (int ni = 0; ni < 4; ni++)
                        acc1[mi][ni] = __builtin_amdgcn_mfma_f32_16x16x32_bf16(
                            af[mi], bfr[ni], acc1[mi][ni], 0, 0, 0);
            } else {
#pragma unroll
                for (int mi = 0; mi < 2; mi++)
#pragma unroll
                    for (int ni = 0; ni < 4; ni++)
                        acc2[mi][ni] = __builtin_amdgcn_mfma_f32_16x16x32_bf16(
                            af[mi], bfr[ni], acc2[mi][ni], 0, 0, 0);
            }
        }

        __builtin_amdgcn_sched_barrier(0);
        __builtin_amdgcn_s_barrier();          // all waves done READING buf -> safe to restage
        __builtin_amdgcn_sched_barrier(0);
        if (kt + 2 < 12) stage(kt + 2, buf);
    }

    // epilogue: C/D layout col=lane&15, row=q*4+reg  [measured m89]
#pragma unroll
    for (int mi = 0; mi < 2; mi++) {
#pragma unroll
        for (int ni = 0; ni < 4; ni++) {
            int d = wnn + ni * 16 + m16;
            float b = bias[d];
#pragma unroll
            for (int r = 0; r < 4; r++) {
                int node = m0 + wm * 32 + mi * 16 + q * 4 + r;
                if (node < N_NODES) {
                    float S  = acc2[mi][ni][r] + b;
                    float sg = 1.f / (1.f + __expf(-S));
                    float ph = prev_h[(size_t)node * DIM + d];
                    float v  = sg * acc1[mi][ni][r] + (1.f - sg) * ph;
                    out[(size_t)node * DIM + d] = fmaxf(v, 0.f);
                }
            }
        }
    }
}

// ---------------- K4: fixup for in_deg==0 nodes (evolve_loop_weight path, exact fp32) --------
__global__ void fixup_kernel(const float* __restrict__ h, const float* __restrict__ prev_h,
                             const float* __restrict__ We, const float* __restrict__ Wsc,
                             const float* __restrict__ bias, const int* __restrict__ wl_count,
                             const int* __restrict__ wl, float* __restrict__ out) {
    __shared__ float ph[DIM], hh[DIM];
    int d = threadIdx.x;
    int cnt = *wl_count;
    for (int i = blockIdx.x; i < cnt; i += gridDim.x) {
        int n = wl[i];
        ph[d] = prev_h[(size_t)n * DIM + d];
        hh[d] = h[(size_t)n * DIM + d];
        __syncthreads();
        float s = 0.f, l = 0.f;
        for (int k = 0; k < DIM; k++) {
            s += ph[k] * Wsc[k * DIM + d];
            l += hh[k] * We[k * DIM + d];
        }
        float sg = 1.f / (1.f + __expf(-(s + bias[d])));
        float v = sg * l + (1.f - sg) * ph[d];
        out[(size_t)n * DIM + d] = fmaxf(v, 0.f);
        __syncthreads();
    }
}

extern "C" void kernel_launch(void* const* d_in, const int* in_sizes, int n_in,
                              void* d_out, int out_size, void* d_ws, size_t ws_size,
                              hipStream_t stream) {
    const float* h      = (const float*)d_in[0];
    const float* prev_h = (const float*)d_in[1];
    const float* emb    = (const float*)d_in[2];
    const float* norm   = (const float*)d_in[3];
    const float* Wn     = (const float*)d_in[4];
    const float* Wl     = (const float*)d_in[5];
    const float* We     = (const float*)d_in[6];
    const float* Wsc    = (const float*)d_in[7];
    const float* bias   = (const float*)d_in[8];
    const int*   src    = (const int*)d_in[9];
    const int*   dstv   = (const int*)d_in[10];
    const int*   et     = (const int*)d_in[11];
    float* out = (float*)d_out;

    char* ws = (char*)d_ws;
    size_t off = 0;
    auto alloc = [&](size_t bytes) -> char* {
        char* p = ws + off; off += (bytes + 255) & ~(size_t)255; return p;
    };
    u16* Xa      = (u16*)alloc((size_t)N_NODES * DIM * 2);   // agg*norm, bf16 dense
    u16* Xh      = (u16*)alloc((size_t)N_NODES * DIM * 2);   // h, bf16 dense
    u16* Xp      = (u16*)alloc((size_t)N_NODES * DIM * 2);   // prev_h, bf16 dense
    u16* embb    = (u16*)alloc((size_t)N_RELS * DIM * 2);
    u16* Wt      = (u16*)alloc((size_t)DIM * KTOT * 2);
    int* deg     = (int*)alloc((size_t)N_NODES * 4);
    int* wlcnt   = (int*)alloc(16);
    int* wl      = (int*)alloc((size_t)N_NODES * 4);
    int* offsets = (int*)alloc((size_t)(N_NODES + 1) * 4);
    int* cursor  = (int*)alloc((size_t)N_NODES * 4);
    unsigned* esee = (unsigned*)alloc((size_t)N_EDGES * 4);
    int* excl    = (int*)alloc((size_t)N_NODES * 4);
    int* bsum    = (int*)alloc((size_t)SCAN_NBLK * 4);
    int* bbase   = (int*)alloc((size_t)SCAN_NBLK * 4);

    // K1: cooperative fused preprocessing (zero + conv + Wt + hist + scan + scatter)
    void* args[] = { (void*)&h, (void*)&emb, (void*)&Wn, (void*)&Wl, (void*)&Wsc,
                     (void*)&src, (void*)&dstv, (void*)&et,
                     (void*)&Xh, (void*)&embb, (void*)&Wt, (void*)&deg, (void*)&wlcnt,
                     (void*)&excl, (void*)&bsum, (void*)&bbase,
                     (void*)&offsets, (void*)&cursor, (void*)&esee };
    hipLaunchCooperativeKernel((const void*)csr_kernel, dim3(COOP_BLKS), dim3(256),
                               args, 0, stream);

    agg_kernel<<<(N_NODES / 2 + 3) / 4, 256, 0, stream>>>(Xh, embb, norm, offsets, esee, prev_h,
                                                          Xa, Xp, wlcnt, wl);
    gemm_kernel<<<(N_NODES + 63) / 64, 512, 0, stream>>>(Xa, Xh, Xp, Wt, prev_h, bias, out);
    fixup_kernel<<<256, 256, 0, stream>>>(h, prev_h, We, Wsc, bias, wlcnt, wl, out);
}

// Round 9
// 304.003 us; speedup vs baseline: 2.8669x; 2.8669x over previous
//
#include <hip/hip_runtime.h>
#include <cstdint>
#include <cstddef>

#define N_NODES 50000
#define N_EDGES 300000
#define DIM     256
#define KTOT    768   // concatenated K: [agg*norm | h | prev_h]
#define N_RELS  500

#define SCAN_BLK  256
#define SCAN_NBLK ((N_NODES + SCAN_BLK - 1) / SCAN_BLK)   // 196

#define CONV_ELEMS ((N_NODES + N_RELS) * DIM)
#define CONV_BLKS  ((CONV_ELEMS / 16 + 255) / 256)        // 16 elems/thread
#define WT_BLKS    48                                     // 3 mats x (4x4) 64x64 tiles
#define HIST_BLKS  ((N_EDGES + 255) / 256)

typedef unsigned short u16;
typedef __attribute__((ext_vector_type(8))) short short8v;   // 8 bf16 = 4 VGPRs (MFMA A/B frag)
typedef __attribute__((ext_vector_type(4))) float float4v;   // MFMA C/D frag

static __device__ __forceinline__ u16 f2bf(float f) {
    union { float f; unsigned u; } v; v.f = f;
    unsigned u = v.u;
    unsigned r = u + 0x7FFFu + ((u >> 16) & 1u);  // RNE
    return (u16)(r >> 16);
}
static __device__ __forceinline__ float bf2f(u16 b) {
    union { unsigned u; float f; } v; v.u = ((unsigned)b) << 16; return v.f;
}

// async global->LDS, 16B per lane, LDS dest = wave-uniform base + lane*16 (linear)
static __device__ __forceinline__ void gld16(const void* g, u16* l) {
    __builtin_amdgcn_global_load_lds(
        (const __attribute__((address_space(1))) unsigned int*)g,
        (__attribute__((address_space(3))) unsigned int*)l,
        16, 0, 0);
}

static __device__ __forceinline__ void conv8(const float* s, u16* d) {
    float4 a = *(const float4*)(s);
    float4 c2 = *(const float4*)(s + 4);
    u16 o8[8] = { f2bf(a.x), f2bf(a.y), f2bf(a.z), f2bf(a.w),
                  f2bf(c2.x), f2bf(c2.y), f2bf(c2.z), f2bf(c2.w) };
    *(uint4*)d = *(const uint4*)o8;
}

// unpack 2x uint4 (8+8 bf16) and accumulate into 8 floats
static __device__ __forceinline__ void acc8(float* a, uint4 hv, uint4 ev) {
    const unsigned* hw = (const unsigned*)&hv;
    const unsigned* ew = (const unsigned*)&ev;
#pragma unroll
    for (int j = 0; j < 4; j++) {
        a[2*j]   += bf2f((u16)(hw[j] & 0xffffu)) + bf2f((u16)(ew[j] & 0xffffu));
        a[2*j+1] += bf2f((u16)(hw[j] >> 16))     + bf2f((u16)(ew[j] >> 16));
    }
}

// ---------------- K1 (fused): conv(h, emb -> bf16, 16/thread) + Wt transpose + hist ------
__global__ void prep_kernel(const float* __restrict__ h, const float* __restrict__ emb,
                            const float* __restrict__ Wn, const float* __restrict__ Wl,
                            const float* __restrict__ Wsc, const int* __restrict__ dstv,
                            u16* __restrict__ Xh, u16* __restrict__ embb,
                            u16* __restrict__ Wt, int* __restrict__ deg) {
    __shared__ float T[64][65];   // transpose tile, 65-pad = conflict-free column reads
    int b = blockIdx.x;
    if (b < CONV_BLKS) {
        int i = b * 256 + threadIdx.x;
        int e0 = i * 16;          // 16 elems/thread; region boundaries are multiples of 16
        if (e0 >= CONV_ELEMS) return;
        const float* s; u16* d;
        if (e0 < N_NODES * DIM) { s = h + e0; d = Xh + e0; }
        else { int o = e0 - N_NODES * DIM; s = emb + o; d = embb + o; }
        conv8(s, d);
        conv8(s + 8, d + 8);
    } else if (b < CONV_BLKS + WT_BLKS) {
        // Wt[d][k] = Wseg[k%256][d], built 64x64-tile-wise: coalesced reads AND writes.
        int tb  = b - CONV_BLKS;
        int mat = tb >> 4;                 // 0..2
        int kb  = (tb & 15) >> 2;          // k-tile 0..3
        int db  = tb & 3;                  // d-tile 0..3
        const float* W = (mat == 0) ? Wn : ((mat == 1) ? Wl : Wsc);
        int c  = threadIdx.x & 63;
        int rq = threadIdx.x >> 6;         // 0..3
#pragma unroll
        for (int p = 0; p < 16; p++) {
            int kk = rq + p * 4;
            T[kk][c] = W[(kb * 64 + kk) * DIM + db * 64 + c];
        }
        __syncthreads();
#pragma unroll
        for (int p = 0; p < 16; p++) {
            int dd = rq + p * 4;
            Wt[(size_t)(db * 64 + dd) * KTOT + mat * 256 + kb * 64 + c] = f2bf(T[c][dd]);
        }
    } else {
        int e = (b - CONV_BLKS - WT_BLKS) * 256 + threadIdx.x;
        if (e < N_EDGES) atomicAdd(&deg[dstv[e]], 1);
    }
}

// ---------------- K2a: per-block scan of deg (proven structure) ----------------
__global__ void scanA_kernel(const int* __restrict__ deg, int* __restrict__ excl_local,
                             int* __restrict__ block_sum) {
    __shared__ int sdata[SCAN_BLK];
    int t = threadIdx.x, i = blockIdx.x * SCAN_BLK + t;
    int v = (i < N_NODES) ? deg[i] : 0;
    sdata[t] = v;
    __syncthreads();
    for (int off = 1; off < SCAN_BLK; off <<= 1) {
        int u = (t >= off) ? sdata[t - off] : 0;
        __syncthreads();
        sdata[t] += u;
        __syncthreads();
    }
    if (i < N_NODES) excl_local[i] = sdata[t] - v;
    if (t == SCAN_BLK - 1) block_sum[blockIdx.x] = sdata[t];
}

// ---------------- K2b: merged scanB+scanC — each block redundantly scans the 196 sums ----
// bsum is 784B, L2-hot after scanA; the redundant 196-wide scan is ~free vs. a launch gap.
__global__ void scanBC_kernel(const int* __restrict__ block_sum, const int* __restrict__ excl_local,
                              int* __restrict__ offsets, int* __restrict__ cursor) {
    __shared__ int sdata[SCAN_BLK];
    int t = threadIdx.x;
    int v = (t < SCAN_NBLK) ? block_sum[t] : 0;
    sdata[t] = v;
    __syncthreads();
    for (int off = 1; off < SCAN_BLK; off <<= 1) {
        int u = (t >= off) ? sdata[t - off] : 0;
        __syncthreads();
        sdata[t] += u;
        __syncthreads();
    }
    // sdata[k] = inclusive sum of block_sum[0..k]
    int base = (blockIdx.x > 0) ? sdata[blockIdx.x - 1] : 0;
    __syncthreads();   // everyone has read sdata; safe (no further writes)
    int i = blockIdx.x * SCAN_BLK + t;
    if (i < N_NODES) {
        int e = base + excl_local[i];
        offsets[i] = e; cursor[i] = e;
    }
    if (blockIdx.x == 0 && t == 0) offsets[N_NODES] = sdata[SCAN_NBLK - 1];
}

// ---------------- K3: scatter edges into CSR slots (packed src*500+et) ----------------
__global__ void scatter_kernel(const int* __restrict__ src, const int* __restrict__ dstv,
                               const int* __restrict__ et, int* __restrict__ cursor,
                               unsigned* __restrict__ esee) {
    int e = blockIdx.x * 256 + threadIdx.x;
    if (e >= N_EDGES) return;
    int d = dstv[e];
    int pos = atomicAdd(&cursor[d], 1);
    esee[pos] = (unsigned)src[e] * N_RELS + (unsigned)et[e];
}

// ---------------- K4: gather-reduce, 2 nodes/wave, 16B loads -> Xa; prev_h -> Xp ----------
// 32 lanes per node, uint4 (8 bf16) per lane; 8 outstanding 16B loads/lane in the 4-edge
// unroll. prev_h conversion streams under the gather latency. (unchanged from R7)
__global__ void agg_kernel(const u16* __restrict__ Xh, const u16* __restrict__ embb,
                           const float* __restrict__ norm, const int* __restrict__ offsets,
                           const unsigned* __restrict__ esee, const float* __restrict__ prev_h,
                           u16* __restrict__ Xa, u16* __restrict__ Xp,
                           int* __restrict__ wl_count, int* __restrict__ wl) {
    int wave = (blockIdx.x * 256 + threadIdx.x) >> 6;
    int half = (threadIdx.x >> 5) & 1;
    int lane32 = threadIdx.x & 31;
    int n = wave * 2 + half;
    if (n >= N_NODES) return;
    int s0 = offsets[n], s1 = offsets[n + 1];
    int c8 = lane32 * 8;
    // prev_h conversion loads issued early — overlap the gather chain
    float4 pa = *(const float4*)(prev_h + (size_t)n * DIM + c8);
    float4 pb = *(const float4*)(prev_h + (size_t)n * DIM + c8 + 4);
    float acc[8] = {0.f, 0.f, 0.f, 0.f, 0.f, 0.f, 0.f, 0.f};
    int e = s0;
    for (; e + 3 < s1; e += 4) {
        unsigned v0 = esee[e], v1 = esee[e + 1], v2 = esee[e + 2], v3 = esee[e + 3];
        unsigned sa = v0 / N_RELS, ta = v0 - sa * N_RELS;
        unsigned sb = v1 / N_RELS, tb = v1 - sb * N_RELS;
        unsigned sc = v2 / N_RELS, tc = v2 - sc * N_RELS;
        unsigned sd = v3 / N_RELS, td = v3 - sd * N_RELS;
        uint4 ha = *(const uint4*)(Xh + (size_t)sa * DIM + c8);
        uint4 ea = *(const uint4*)(embb + (size_t)ta * DIM + c8);
        uint4 hb = *(const uint4*)(Xh + (size_t)sb * DIM + c8);
        uint4 eb = *(const uint4*)(embb + (size_t)tb * DIM + c8);
        uint4 hc = *(const uint4*)(Xh + (size_t)sc * DIM + c8);
        uint4 ec = *(const uint4*)(embb + (size_t)tc * DIM + c8);
        uint4 hd = *(const uint4*)(Xh + (size_t)sd * DIM + c8);
        uint4 ed = *(const uint4*)(embb + (size_t)td * DIM + c8);
        acc8(acc, ha, ea); acc8(acc, hb, eb); acc8(acc, hc, ec); acc8(acc, hd, ed);
    }
    for (; e < s1; e++) {
        unsigned v = esee[e];
        unsigned s = v / N_RELS;
        unsigned t = v - s * N_RELS;
        uint4 hv = *(const uint4*)(Xh + (size_t)s * DIM + c8);
        uint4 ev = *(const uint4*)(embb + (size_t)t * DIM + c8);
        acc8(acc, hv, ev);
    }
    float nr = norm[n];
    u16 o[8];
#pragma unroll
    for (int j = 0; j < 8; j++) o[j] = f2bf(acc[j] * nr);
    *(uint4*)(Xa + (size_t)n * DIM + c8) = *(const uint4*)o;
    u16 p8[8] = { f2bf(pa.x), f2bf(pa.y), f2bf(pa.z), f2bf(pa.w),
                  f2bf(pb.x), f2bf(pb.y), f2bf(pb.z), f2bf(pb.w) };
    *(uint4*)(Xp + (size_t)n * DIM + c8) = *(const uint4*)p8;
    if (lane32 == 0 && s1 == s0) { int idx = atomicAdd(wl_count, 1); wl[idx] = n; }
}

// ---------------- K5: fused MFMA GEMM, counted-vmcnt, 8-wave high-occupancy ----------------
// R4 proven structure, unchanged. A sources: Xa kt0-3, Xh kt4-7, Xp kt8-11 (compile-time
// select under the unrolled kt loop). 5 gld16/thread/tile; head waits vmcnt(5) (T4).
// Swizzle: source chunk pre-XOR (lc8^lr), linear LDS dest, read chunk XOR (m16&7)<<3.
// LDS: A dbuf 2x8KB @u16[0/4096], B dbuf 2x32KB @u16[8192/24576] = 80KB -> 2 blocks/CU.
__launch_bounds__(512, 4)
__global__ void gemm_kernel(const u16* __restrict__ Xa, const u16* __restrict__ Xh,
                            const u16* __restrict__ Xp, const u16* __restrict__ Wt,
                            const float* __restrict__ prev_h, const float* __restrict__ bias,
                            float* __restrict__ out) {
    __shared__ __align__(16) u16 lds[40960];   // 81920 B
    int tid  = threadIdx.x;
    int wave = tid >> 6, lane = tid & 63, q = lane >> 4, m16 = lane & 15;
    int wm = wave >> 2;              // M-group: rows [wm*32, +32)
    int wnn = (wave & 3) * 64;       // N-group: cols [wnn, +64)
    int m0 = blockIdx.x * 64;
    int lr = lane >> 3, lc8 = lane & 7;        // staging: row-in-issue / 16B-chunk
    int sc8 = (lc8 ^ lr) << 3;                 // pre-swizzled source chunk (u16 units)

    // A staging: wave stages rows [wave*8, +8)  (8 waves cover 64 rows)
    int arow = wave * 8 + lr;
    int ga = (m0 + arow < N_NODES) ? (m0 + arow) : (N_NODES - 1);
    const u16* sAa = Xa + (size_t)ga * DIM + sc8;
    const u16* sAh = Xh + (size_t)ga * DIM + sc8;
    const u16* sAp = Xp + (size_t)ga * DIM + sc8;
    // B staging: wave stages Wt rows [wave*32, +32) in 4 issues of 8 rows
    const u16* sB = Wt + (size_t)(wave * 32 + lr) * KTOT + sc8;

    float4v acc1[2][4], acc2[2][4];
#pragma unroll
    for (int i = 0; i < 2; i++)
#pragma unroll
        for (int j = 0; j < 4; j++) { acc1[i][j] = (float4v)0.f; acc2[i][j] = (float4v)0.f; }

    auto stage = [&](int kt, int buf) {
#pragma unroll
        for (int j = 0; j < 4; j++)
            gld16(sB + (size_t)j * 8 * KTOT + kt * 64,
                  &lds[8192 + buf * 16384 + wave * 2048 + j * 512]);
        const u16* base = (kt < 4) ? sAa : ((kt < 8) ? sAh : sAp);
        gld16(base + (kt & 3) * 64, &lds[buf * 4096 + wave * 512]);
    };

    // prologue: tiles 0 and 1 in flight (10 outstanding per thread)
    stage(0, 0);
    stage(1, 1);

    int sw = (m16 & 7) << 3;   // read-side swizzle (u16 units)

#pragma unroll
    for (int kt = 0; kt < 12; kt++) {
        int buf = kt & 1;
        // wait for MY tile-kt loads only; tile-kt+1's 5 stay in flight (T4)
        if (kt < 11) asm volatile("s_waitcnt vmcnt(5)" ::: "memory");
        else         asm volatile("s_waitcnt vmcnt(0)" ::: "memory");
        __builtin_amdgcn_sched_barrier(0);
        __builtin_amdgcn_s_barrier();          // every wave's tile-kt data now in LDS
        __builtin_amdgcn_sched_barrier(0);

#pragma unroll
        for (int kk = 0; kk < 2; kk++) {
            int ck = (kk * 32 + q * 8) ^ sw;
            short8v af[2], bfr[4];
#pragma unroll
            for (int mi = 0; mi < 2; mi++)
                af[mi] = *(const short8v*)(&lds[buf * 4096 + (wm * 32 + mi * 16 + m16) * 64 + ck]);
#pragma unroll
            for (int ni = 0; ni < 4; ni++)
                bfr[ni] = *(const short8v*)(&lds[8192 + buf * 16384 + (wnn + ni * 16 + m16) * 64 + ck]);
            if (kt < 8) {
#pragma unroll
                for (int mi = 0; mi < 2; mi++)
#pragma unroll
                    for (int ni = 0; ni < 4; ni++)
                        acc1[mi][ni] = __builtin_amdgcn_mfma_f32_16x16x32_bf16(
                            af[mi], bfr[ni], acc1[mi][ni], 0, 0, 0);
            } else {
#pragma unroll
                for (int mi = 0; mi < 2; mi++)
#pragma unroll
                    for (int ni = 0; ni < 4; ni++)
                        acc2[mi][ni] = __builtin_amdgcn_mfma_f32_16x16x32_bf16(
                            af[mi], bfr[ni], acc2[mi][ni], 0, 0, 0);
            }
        }

        __builtin_amdgcn_sched_barrier(0);
        __builtin_amdgcn_s_barrier();          // all waves done READING buf -> safe to restage
        __builtin_amdgcn_sched_barrier(0);
        if (kt + 2 < 12) stage(kt + 2, buf);
    }

    // epilogue: C/D layout col=lane&15, row=q*4+reg  [measured m89]
#pragma unroll
    for (int mi = 0; mi < 2; mi++) {
#pragma unroll
        for (int ni = 0; ni < 4; ni++) {
            int d = wnn + ni * 16 + m16;
            float b = bias[d];
#pragma unroll
            for (int r = 0; r < 4; r++) {
                int node = m0 + wm * 32 + mi * 16 + q * 4 + r;
                if (node < N_NODES) {
                    float S  = acc2[mi][ni][r] + b;
                    float sg = 1.f / (1.f + __expf(-S));
                    float ph = prev_h[(size_t)node * DIM + d];
                    float v  = sg * acc1[mi][ni][r] + (1.f - sg) * ph;
                    out[(size_t)node * DIM + d] = fmaxf(v, 0.f);
                }
            }
        }
    }
}

// ---------------- K6: fixup for in_deg==0 nodes (evolve_loop_weight path, exact fp32) --------
__global__ void fixup_kernel(const float* __restrict__ h, const float* __restrict__ prev_h,
                             const float* __restrict__ We, const float* __restrict__ Wsc,
                             const float* __restrict__ bias, const int* __restrict__ wl_count,
                             const int* __restrict__ wl, float* __restrict__ out) {
    __shared__ float ph[DIM], hh[DIM];
    int d = threadIdx.x;
    int cnt = *wl_count;
    for (int i = blockIdx.x; i < cnt; i += gridDim.x) {
        int n = wl[i];
        ph[d] = prev_h[(size_t)n * DIM + d];
        hh[d] = h[(size_t)n * DIM + d];
        __syncthreads();
        float s = 0.f, l = 0.f;
        for (int k = 0; k < DIM; k++) {
            s += ph[k] * Wsc[k * DIM + d];
            l += hh[k] * We[k * DIM + d];
        }
        float sg = 1.f / (1.f + __expf(-(s + bias[d])));
        float v = sg * l + (1.f - sg) * ph[d];
        out[(size_t)n * DIM + d] = fmaxf(v, 0.f);
        __syncthreads();
    }
}

extern "C" void kernel_launch(void* const* d_in, const int* in_sizes, int n_in,
                              void* d_out, int out_size, void* d_ws, size_t ws_size,
                              hipStream_t stream) {
    const float* h      = (const float*)d_in[0];
    const float* prev_h = (const float*)d_in[1];
    const float* emb    = (const float*)d_in[2];
    const float* norm   = (const float*)d_in[3];
    const float* Wn     = (const float*)d_in[4];
    const float* Wl     = (const float*)d_in[5];
    const float* We     = (const float*)d_in[6];
    const float* Wsc    = (const float*)d_in[7];
    const float* bias   = (const float*)d_in[8];
    const int*   src    = (const int*)d_in[9];
    const int*   dstv   = (const int*)d_in[10];
    const int*   et     = (const int*)d_in[11];
    float* out = (float*)d_out;

    char* ws = (char*)d_ws;
    size_t off = 0;
    auto alloc = [&](size_t bytes) -> char* {
        char* p = ws + off; off += (bytes + 255) & ~(size_t)255; return p;
    };
    u16* Xa      = (u16*)alloc((size_t)N_NODES * DIM * 2);   // agg*norm, bf16 dense
    u16* Xh      = (u16*)alloc((size_t)N_NODES * DIM * 2);   // h, bf16 dense
    u16* Xp      = (u16*)alloc((size_t)N_NODES * DIM * 2);   // prev_h, bf16 dense
    u16* embb    = (u16*)alloc((size_t)N_RELS * DIM * 2);
    u16* Wt      = (u16*)alloc((size_t)DIM * KTOT * 2);
    int* deg     = (int*)alloc((size_t)N_NODES * 4);         // deg + wlcnt: ONE memset
    int* wlcnt   = (int*)alloc(16);                          // (contiguous after deg pad)
    int* wl      = (int*)alloc((size_t)N_NODES * 4);
    int* offsets = (int*)alloc((size_t)(N_NODES + 1) * 4);
    int* cursor  = (int*)alloc((size_t)N_NODES * 4);
    unsigned* esee = (unsigned*)alloc((size_t)N_EDGES * 4);
    int* excl    = (int*)alloc((size_t)N_NODES * 4);
    int* bsum    = (int*)alloc((size_t)SCAN_NBLK * 4);

    // single memset spans deg (padded to 256) + wlcnt
    size_t deg_span = (((size_t)N_NODES * 4 + 255) & ~(size_t)255) + 16;
    hipMemsetAsync(deg, 0, deg_span, stream);

    prep_kernel<<<CONV_BLKS + WT_BLKS + HIST_BLKS, 256, 0, stream>>>(
        h, emb, Wn, Wl, Wsc, dstv, Xh, embb, Wt, deg);
    scanA_kernel<<<SCAN_NBLK, SCAN_BLK, 0, stream>>>(deg, excl, bsum);
    scanBC_kernel<<<SCAN_NBLK, SCAN_BLK, 0, stream>>>(bsum, excl, offsets, cursor);
    scatter_kernel<<<(N_EDGES + 255) / 256, 256, 0, stream>>>(src, dstv, et, cursor, esee);
    agg_kernel<<<(N_NODES / 2 + 3) / 4, 256, 0, stream>>>(Xh, embb, norm, offsets, esee, prev_h,
                                                          Xa, Xp, wlcnt, wl);
    gemm_kernel<<<(N_NODES + 63) / 64, 512, 0, stream>>>(Xa, Xh, Xp, Wt, prev_h, bias, out);
    fixup_kernel<<<256, 256, 0, stream>>>(h, prev_h, We, Wsc, bias, wlcnt, wl, out);
}

// Round 10
// 302.434 us; speedup vs baseline: 2.8817x; 1.0052x over previous
//
#include <hip/hip_runtime.h>
#include <cstdint>
#include <cstddef>

#define N_NODES 50000
#define N_EDGES 300000
#define DIM     256
#define KTOT    768   // concatenated K: [agg*norm | h | prev_h]
#define N_RELS  500

#define SCAN_BLK  256
#define SCAN_NBLK ((N_NODES + SCAN_BLK - 1) / SCAN_BLK)   // 196

#define CONV_ELEMS ((N_NODES + N_RELS) * DIM)
#define CONV_BLKS  ((CONV_ELEMS / 16 + 255) / 256)        // 16 elems/thread
#define WT_BLKS    48                                     // 3 mats x (4x4) 64x64 tiles
#define HIST_BLKS  ((N_EDGES + 255) / 256)

typedef unsigned short u16;
typedef __attribute__((ext_vector_type(8))) short short8v;   // 8 bf16 = 4 VGPRs (MFMA A/B frag)
typedef __attribute__((ext_vector_type(4))) float float4v;   // MFMA C/D frag

static __device__ __forceinline__ u16 f2bf(float f) {
    union { float f; unsigned u; } v; v.f = f;
    unsigned u = v.u;
    unsigned r = u + 0x7FFFu + ((u >> 16) & 1u);  // RNE
    return (u16)(r >> 16);
}
static __device__ __forceinline__ float bf2f(u16 b) {
    union { unsigned u; float f; } v; v.u = ((unsigned)b) << 16; return v.f;
}

// async global->LDS, 16B per lane, LDS dest = wave-uniform base + lane*16 (linear)
static __device__ __forceinline__ void gld16(const void* g, u16* l) {
    __builtin_amdgcn_global_load_lds(
        (const __attribute__((address_space(1))) unsigned int*)g,
        (__attribute__((address_space(3))) unsigned int*)l,
        16, 0, 0);
}

static __device__ __forceinline__ void conv8(const float* s, u16* d) {
    float4 a = *(const float4*)(s);
    float4 c2 = *(const float4*)(s + 4);
    u16 o8[8] = { f2bf(a.x), f2bf(a.y), f2bf(a.z), f2bf(a.w),
                  f2bf(c2.x), f2bf(c2.y), f2bf(c2.z), f2bf(c2.w) };
    *(uint4*)d = *(const uint4*)o8;
}

// unpack 2x uint4 (8+8 bf16) and accumulate into 8 floats
static __device__ __forceinline__ void acc8(float* a, uint4 hv, uint4 ev) {
    const unsigned* hw = (const unsigned*)&hv;
    const unsigned* ew = (const unsigned*)&ev;
#pragma unroll
    for (int j = 0; j < 4; j++) {
        a[2*j]   += bf2f((u16)(hw[j] & 0xffffu)) + bf2f((u16)(ew[j] & 0xffffu));
        a[2*j+1] += bf2f((u16)(hw[j] >> 16))     + bf2f((u16)(ew[j] >> 16));
    }
}

// ---------------- K1 (fused): conv(h, emb -> bf16, 16/thread) + Wt transpose + hist ------
__global__ void prep_kernel(const float* __restrict__ h, const float* __restrict__ emb,
                            const float* __restrict__ Wn, const float* __restrict__ Wl,
                            const float* __restrict__ Wsc, const int* __restrict__ dstv,
                            u16* __restrict__ Xh, u16* __restrict__ embb,
                            u16* __restrict__ Wt, int* __restrict__ deg) {
    __shared__ float T[64][65];   // transpose tile, 65-pad = conflict-free column reads
    int b = blockIdx.x;
    if (b < CONV_BLKS) {
        int i = b * 256 + threadIdx.x;
        int e0 = i * 16;          // 16 elems/thread; region boundaries are multiples of 16
        if (e0 >= CONV_ELEMS) return;
        const float* s; u16* d;
        if (e0 < N_NODES * DIM) { s = h + e0; d = Xh + e0; }
        else { int o = e0 - N_NODES * DIM; s = emb + o; d = embb + o; }
        conv8(s, d);
        conv8(s + 8, d + 8);
    } else if (b < CONV_BLKS + WT_BLKS) {
        // Wt[d][k] = Wseg[k%256][d], built 64x64-tile-wise: coalesced reads AND writes.
        int tb  = b - CONV_BLKS;
        int mat = tb >> 4;                 // 0..2
        int kb  = (tb & 15) >> 2;          // k-tile 0..3
        int db  = tb & 3;                  // d-tile 0..3
        const float* W = (mat == 0) ? Wn : ((mat == 1) ? Wl : Wsc);
        int c  = threadIdx.x & 63;
        int rq = threadIdx.x >> 6;         // 0..3
#pragma unroll
        for (int p = 0; p < 16; p++) {
            int kk = rq + p * 4;
            T[kk][c] = W[(kb * 64 + kk) * DIM + db * 64 + c];
        }
        __syncthreads();
#pragma unroll
        for (int p = 0; p < 16; p++) {
            int dd = rq + p * 4;
            Wt[(size_t)(db * 64 + dd) * KTOT + mat * 256 + kb * 64 + c] = f2bf(T[c][dd]);
        }
    } else {
        int e = (b - CONV_BLKS - WT_BLKS) * 256 + threadIdx.x;
        if (e < N_EDGES) atomicAdd(&deg[dstv[e]], 1);
    }
}

// ---------------- K2a: per-block scan of deg (proven structure) ----------------
__global__ void scanA_kernel(const int* __restrict__ deg, int* __restrict__ excl_local,
                             int* __restrict__ block_sum) {
    __shared__ int sdata[SCAN_BLK];
    int t = threadIdx.x, i = blockIdx.x * SCAN_BLK + t;
    int v = (i < N_NODES) ? deg[i] : 0;
    sdata[t] = v;
    __syncthreads();
    for (int off = 1; off < SCAN_BLK; off <<= 1) {
        int u = (t >= off) ? sdata[t - off] : 0;
        __syncthreads();
        sdata[t] += u;
        __syncthreads();
    }
    if (i < N_NODES) excl_local[i] = sdata[t] - v;
    if (t == SCAN_BLK - 1) block_sum[blockIdx.x] = sdata[t];
}

// ---------------- K2b: merged scanB+scanC — each block redundantly scans the 196 sums ----
__global__ void scanBC_kernel(const int* __restrict__ block_sum, const int* __restrict__ excl_local,
                              int* __restrict__ offsets, int* __restrict__ cursor) {
    __shared__ int sdata[SCAN_BLK];
    int t = threadIdx.x;
    int v = (t < SCAN_NBLK) ? block_sum[t] : 0;
    sdata[t] = v;
    __syncthreads();
    for (int off = 1; off < SCAN_BLK; off <<= 1) {
        int u = (t >= off) ? sdata[t - off] : 0;
        __syncthreads();
        sdata[t] += u;
        __syncthreads();
    }
    int base = (blockIdx.x > 0) ? sdata[blockIdx.x - 1] : 0;
    __syncthreads();
    int i = blockIdx.x * SCAN_BLK + t;
    if (i < N_NODES) {
        int e = base + excl_local[i];
        offsets[i] = e; cursor[i] = e;
    }
    if (blockIdx.x == 0 && t == 0) offsets[N_NODES] = sdata[SCAN_NBLK - 1];
}

// ---------------- K3: scatter edges into CSR slots (packed src*500+et) ----------------
__global__ void scatter_kernel(const int* __restrict__ src, const int* __restrict__ dstv,
                               const int* __restrict__ et, int* __restrict__ cursor,
                               unsigned* __restrict__ esee) {
    int e = blockIdx.x * 256 + threadIdx.x;
    if (e >= N_EDGES) return;
    int d = dstv[e];
    int pos = atomicAdd(&cursor[d], 1);
    esee[pos] = (unsigned)src[e] * N_RELS + (unsigned)et[e];
}

// ---------------- K4: gather-reduce, 2 nodes/wave, 16B loads -> Xa; prev_h -> Xp ----------
__global__ void agg_kernel(const u16* __restrict__ Xh, const u16* __restrict__ embb,
                           const float* __restrict__ norm, const int* __restrict__ offsets,
                           const unsigned* __restrict__ esee, const float* __restrict__ prev_h,
                           u16* __restrict__ Xa, u16* __restrict__ Xp,
                           int* __restrict__ wl_count, int* __restrict__ wl) {
    int wave = (blockIdx.x * 256 + threadIdx.x) >> 6;
    int half = (threadIdx.x >> 5) & 1;
    int lane32 = threadIdx.x & 31;
    int n = wave * 2 + half;
    if (n >= N_NODES) return;
    int s0 = offsets[n], s1 = offsets[n + 1];
    int c8 = lane32 * 8;
    // prev_h conversion loads issued early — overlap the gather chain
    float4 pa = *(const float4*)(prev_h + (size_t)n * DIM + c8);
    float4 pb = *(const float4*)(prev_h + (size_t)n * DIM + c8 + 4);
    float acc[8] = {0.f, 0.f, 0.f, 0.f, 0.f, 0.f, 0.f, 0.f};
    int e = s0;
    for (; e + 3 < s1; e += 4) {
        unsigned v0 = esee[e], v1 = esee[e + 1], v2 = esee[e + 2], v3 = esee[e + 3];
        unsigned sa = v0 / N_RELS, ta = v0 - sa * N_RELS;
        unsigned sb = v1 / N_RELS, tb = v1 - sb * N_RELS;
        unsigned sc = v2 / N_RELS, tc = v2 - sc * N_RELS;
        unsigned sd = v3 / N_RELS, td = v3 - sd * N_RELS;
        uint4 ha = *(const uint4*)(Xh + (size_t)sa * DIM + c8);
        uint4 ea = *(const uint4*)(embb + (size_t)ta * DIM + c8);
        uint4 hb = *(const uint4*)(Xh + (size_t)sb * DIM + c8);
        uint4 eb = *(const uint4*)(embb + (size_t)tb * DIM + c8);
        uint4 hc = *(const uint4*)(Xh + (size_t)sc * DIM + c8);
        uint4 ec = *(const uint4*)(embb + (size_t)tc * DIM + c8);
        uint4 hd = *(const uint4*)(Xh + (size_t)sd * DIM + c8);
        uint4 ed = *(const uint4*)(embb + (size_t)td * DIM + c8);
        acc8(acc, ha, ea); acc8(acc, hb, eb); acc8(acc, hc, ec); acc8(acc, hd, ed);
    }
    for (; e < s1; e++) {
        unsigned v = esee[e];
        unsigned s = v / N_RELS;
        unsigned t = v - s * N_RELS;
        uint4 hv = *(const uint4*)(Xh + (size_t)s * DIM + c8);
        uint4 ev = *(const uint4*)(embb + (size_t)t * DIM + c8);
        acc8(acc, hv, ev);
    }
    float nr = norm[n];
    u16 o[8];
#pragma unroll
    for (int j = 0; j < 8; j++) o[j] = f2bf(acc[j] * nr);
    *(uint4*)(Xa + (size_t)n * DIM + c8) = *(const uint4*)o;
    u16 p8[8] = { f2bf(pa.x), f2bf(pa.y), f2bf(pa.z), f2bf(pa.w),
                  f2bf(pb.x), f2bf(pb.y), f2bf(pb.z), f2bf(pb.w) };
    *(uint4*)(Xp + (size_t)n * DIM + c8) = *(const uint4*)p8;
    if (lane32 == 0 && s1 == s0) { int idx = atomicAdd(wl_count, 1); wl[idx] = n; }
}

// ---------------- K5: fused MFMA GEMM, counted-vmcnt, 48KB-LDS 3-blocks/CU ----------------
// R4 schedule, tile split in N: block = 64 nodes x 128 cols (grid x2). LDS = A dbuf 2x8KB
// + B dbuf 2x16KB = 48KB -> 3 blocks/CU (R9 post-mortem: 80KB LDS = 2x81920 = exactly
// 160KB never fit 2 blocks; occupancy was stuck at 1 block/CU all session).
// 8 waves (2M x 4N): wave (wm=wave&1, wc=wave>>1) owns rows [wm*32,+32) x cols [wc*32,+32).
// Staging: 3 gld16/thread/tile (2 B + 1 A); head waits vmcnt(3) (tile kt+1 in flight, T4).
// Swizzle unchanged: source chunk pre-XOR (lc8^lr), linear dest, read XOR (m16&7)<<3.
__launch_bounds__(512, 6)
__global__ void gemm_kernel(const u16* __restrict__ Xa, const u16* __restrict__ Xh,
                            const u16* __restrict__ Xp, const u16* __restrict__ Wt,
                            const float* __restrict__ prev_h, const float* __restrict__ bias,
                            float* __restrict__ out) {
    __shared__ __align__(16) u16 lds[24576];   // 49152 B
    int tid  = threadIdx.x;
    int wave = tid >> 6, lane = tid & 63, q = lane >> 4, m16 = lane & 15;
    int wm = wave & 1;               // M-group: rows [wm*32, +32)
    int wc = wave >> 1;              // N-group: cols [wc*32, +32) within the 128-col slab
    int m0   = (blockIdx.x >> 1) * 64;
    int col0 = (blockIdx.x & 1) * 128;
    int lr = lane >> 3, lc8 = lane & 7;        // staging: row-in-issue / 16B-chunk
    int sc8 = (lc8 ^ lr) << 3;                 // pre-swizzled source chunk (u16 units)

    // A staging: wave stages rows [wave*8, +8)  (8 waves cover 64 rows)
    int arow = wave * 8 + lr;
    int ga = (m0 + arow < N_NODES) ? (m0 + arow) : (N_NODES - 1);
    const u16* sAa = Xa + (size_t)ga * DIM + sc8;
    const u16* sAh = Xh + (size_t)ga * DIM + sc8;
    const u16* sAp = Xp + (size_t)ga * DIM + sc8;
    // B staging: wave stages Wt rows [col0 + wave*16, +16) in 2 issues of 8 rows
    const u16* sB = Wt + (size_t)(col0 + wave * 16 + lr) * KTOT + sc8;
    int ldsB_w = 8192 + wave * 1024;           // + buf*8192 + j*512

    float4v acc1[2][2], acc2[2][2];
#pragma unroll
    for (int i = 0; i < 2; i++)
#pragma unroll
        for (int j = 0; j < 2; j++) { acc1[i][j] = (float4v)0.f; acc2[i][j] = (float4v)0.f; }

    auto stage = [&](int kt, int buf) {
#pragma unroll
        for (int j = 0; j < 2; j++)
            gld16(sB + (size_t)j * 8 * KTOT + kt * 64,
                  &lds[ldsB_w + buf * 8192 + j * 512]);
        const u16* base = (kt < 4) ? sAa : ((kt < 8) ? sAh : sAp);
        gld16(base + (kt & 3) * 64, &lds[buf * 4096 + wave * 512]);
    };

    // prologue: tiles 0 and 1 in flight (6 outstanding per thread)
    stage(0, 0);
    stage(1, 1);

    int sw = (m16 & 7) << 3;   // read-side swizzle (u16 units)

#pragma unroll
    for (int kt = 0; kt < 12; kt++) {
        int buf = kt & 1;
        // wait for MY tile-kt loads only; tile-kt+1's 3 stay in flight (T4)
        if (kt < 11) asm volatile("s_waitcnt vmcnt(3)" ::: "memory");
        else         asm volatile("s_waitcnt vmcnt(0)" ::: "memory");
        __builtin_amdgcn_sched_barrier(0);
        __builtin_amdgcn_s_barrier();          // every wave's tile-kt data now in LDS
        __builtin_amdgcn_sched_barrier(0);

#pragma unroll
        for (int kk = 0; kk < 2; kk++) {
            int ck = (kk * 32 + q * 8) ^ sw;
            short8v af[2], bfr[2];
#pragma unroll
            for (int mi = 0; mi < 2; mi++)
                af[mi] = *(const short8v*)(&lds[buf * 4096 + (wm * 32 + mi * 16 + m16) * 64 + ck]);
#pragma unroll
            for (int ni = 0; ni < 2; ni++)
                bfr[ni] = *(const short8v*)(&lds[8192 + buf * 8192 + (wc * 32 + ni * 16 + m16) * 64 + ck]);
            if (kt < 8) {
#pragma unroll
                for (int mi = 0; mi < 2; mi++)
#pragma unroll
                    for (int ni = 0; ni < 2; ni++)
                        acc1[mi][ni] = __builtin_amdgcn_mfma_f32_16x16x32_bf16(
                            af[mi], bfr[ni], acc1[mi][ni], 0, 0, 0);
            } else {
#pragma unroll
                for (int mi = 0; mi < 2; mi++)
#pragma unroll
                    for (int ni = 0; ni < 2; ni++)
                        acc2[mi][ni] = __builtin_amdgcn_mfma_f32_16x16x32_bf16(
                            af[mi], bfr[ni], acc2[mi][ni], 0, 0, 0);
            }
        }

        __builtin_amdgcn_sched_barrier(0);
        __builtin_amdgcn_s_barrier();          // all waves done READING buf -> safe to restage
        __builtin_amdgcn_sched_barrier(0);
        if (kt + 2 < 12) stage(kt + 2, buf);
    }

    // epilogue: C/D layout col=lane&15, row=q*4+reg  [measured m89]
#pragma unroll
    for (int mi = 0; mi < 2; mi++) {
#pragma unroll
        for (int ni = 0; ni < 2; ni++) {
            int d = col0 + wc * 32 + ni * 16 + m16;
            float b = bias[d];
#pragma unroll
            for (int r = 0; r < 4; r++) {
                int node = m0 + wm * 32 + mi * 16 + q * 4 + r;
                if (node < N_NODES) {
                    float S  = acc2[mi][ni][r] + b;
                    float sg = 1.f / (1.f + __expf(-S));
                    float ph = prev_h[(size_t)node * DIM + d];
                    float v  = sg * acc1[mi][ni][r] + (1.f - sg) * ph;
                    out[(size_t)node * DIM + d] = fmaxf(v, 0.f);
                }
            }
        }
    }
}

// ---------------- K6: fixup for in_deg==0 nodes (evolve_loop_weight path, exact fp32) --------
__global__ void fixup_kernel(const float* __restrict__ h, const float* __restrict__ prev_h,
                             const float* __restrict__ We, const float* __restrict__ Wsc,
                             const float* __restrict__ bias, const int* __restrict__ wl_count,
                             const int* __restrict__ wl, float* __restrict__ out) {
    __shared__ float ph[DIM], hh[DIM];
    int d = threadIdx.x;
    int cnt = *wl_count;
    for (int i = blockIdx.x; i < cnt; i += gridDim.x) {
        int n = wl[i];
        ph[d] = prev_h[(size_t)n * DIM + d];
        hh[d] = h[(size_t)n * DIM + d];
        __syncthreads();
        float s = 0.f, l = 0.f;
        for (int k = 0; k < DIM; k++) {
            s += ph[k] * Wsc[k * DIM + d];
            l += hh[k] * We[k * DIM + d];
        }
        float sg = 1.f / (1.f + __expf(-(s + bias[d])));
        float v = sg * l + (1.f - sg) * ph[d];
        out[(size_t)n * DIM + d] = fmaxf(v, 0.f);
        __syncthreads();
    }
}

extern "C" void kernel_launch(void* const* d_in, const int* in_sizes, int n_in,
                              void* d_out, int out_size, void* d_ws, size_t ws_size,
                              hipStream_t stream) {
    const float* h      = (const float*)d_in[0];
    const float* prev_h = (const float*)d_in[1];
    const float* emb    = (const float*)d_in[2];
    const float* norm   = (const float*)d_in[3];
    const float* Wn     = (const float*)d_in[4];
    const float* Wl     = (const float*)d_in[5];
    const float* We     = (const float*)d_in[6];
    const float* Wsc    = (const float*)d_in[7];
    const float* bias   = (const float*)d_in[8];
    const int*   src    = (const int*)d_in[9];
    const int*   dstv   = (const int*)d_in[10];
    const int*   et     = (const int*)d_in[11];
    float* out = (float*)d_out;

    char* ws = (char*)d_ws;
    size_t off = 0;
    auto alloc = [&](size_t bytes) -> char* {
        char* p = ws + off; off += (bytes + 255) & ~(size_t)255; return p;
    };
    u16* Xa      = (u16*)alloc((size_t)N_NODES * DIM * 2);   // agg*norm, bf16 dense
    u16* Xh      = (u16*)alloc((size_t)N_NODES * DIM * 2);   // h, bf16 dense
    u16* Xp      = (u16*)alloc((size_t)N_NODES * DIM * 2);   // prev_h, bf16 dense
    u16* embb    = (u16*)alloc((size_t)N_RELS * DIM * 2);
    u16* Wt      = (u16*)alloc((size_t)DIM * KTOT * 2);
    int* deg     = (int*)alloc((size_t)N_NODES * 4);         // deg + wlcnt: ONE memset
    int* wlcnt   = (int*)alloc(16);                          // (contiguous after deg pad)
    int* wl      = (int*)alloc((size_t)N_NODES * 4);
    int* offsets = (int*)alloc((size_t)(N_NODES + 1) * 4);
    int* cursor  = (int*)alloc((size_t)N_NODES * 4);
    unsigned* esee = (unsigned*)alloc((size_t)N_EDGES * 4);
    int* excl    = (int*)alloc((size_t)N_NODES * 4);
    int* bsum    = (int*)alloc((size_t)SCAN_NBLK * 4);

    // single memset spans deg (padded to 256) + wlcnt
    size_t deg_span = (((size_t)N_NODES * 4 + 255) & ~(size_t)255) + 16;
    hipMemsetAsync(deg, 0, deg_span, stream);

    prep_kernel<<<CONV_BLKS + WT_BLKS + HIST_BLKS, 256, 0, stream>>>(
        h, emb, Wn, Wl, Wsc, dstv, Xh, embb, Wt, deg);
    scanA_kernel<<<SCAN_NBLK, SCAN_BLK, 0, stream>>>(deg, excl, bsum);
    scanBC_kernel<<<SCAN_NBLK, SCAN_BLK, 0, stream>>>(bsum, excl, offsets, cursor);
    scatter_kernel<<<(N_EDGES + 255) / 256, 256, 0, stream>>>(src, dstv, et, cursor, esee);
    agg_kernel<<<(N_NODES / 2 + 3) / 4, 256, 0, stream>>>(Xh, embb, norm, offsets, esee, prev_h,
                                                          Xa, Xp, wlcnt, wl);
    gemm_kernel<<<((N_NODES + 63) / 64) * 2, 512, 0, stream>>>(Xa, Xh, Xp, Wt, prev_h, bias, out);
    fixup_kernel<<<256, 256, 0, stream>>>(h, prev_h, We, Wsc, bias, wlcnt, wl, out);
}